// Round 17
// baseline (116.608 us; speedup 1.0000x reference)
//
#include <hip/hip_runtime.h>
#include <hip/hip_bf16.h>

typedef __attribute__((ext_vector_type(8))) short short8;
typedef __attribute__((ext_vector_type(8))) unsigned short ushort8;
typedef __attribute__((ext_vector_type(4))) float f32x4;
typedef __attribute__((ext_vector_type(4))) int int4v;
typedef __attribute__((ext_vector_type(4))) float float4v;
typedef __attribute__((ext_vector_type(2))) float float2v;
typedef __attribute__((ext_vector_type(4))) unsigned int uint4v;

#define HH 128
#define WW 256
#define CIN_ 128
#define COUT_ 128

__device__ __forceinline__ unsigned short f2bf(float f) {
  union { __hip_bfloat16 h; unsigned short u; } v;
  v.h = __float2bfloat16(f);
  return v.u;
}

// ---------------- merged prep #1: T (288 blk) + nhwc (2048 blk) + meta (1152 blk)
__global__ __launch_bounds__(256) void k_pre1(
    const float* __restrict__ down_w, const float* __restrict__ weight,
    float* __restrict__ T,
    const float* __restrict__ x, unsigned short* __restrict__ xh,
    const float* __restrict__ offset, int4v* __restrict__ mo,
    float4v* __restrict__ mw) {
  __shared__ float tile[32 * 129];
  int bid = blockIdx.x;
  int tid = threadIdx.x;

  if (bid < 288) {
    int e = bid * 256 + tid;
    if (e >= 2 * 32 * 1152) return;
    int s = e / 36864, r = e % 36864, d = r / 1152, ck = r % 1152;
    float a = 0.f;
    #pragma unroll 4
    for (int p = 0; p < 128; ++p)
      a += down_w[d * 256 + s * 128 + p] * weight[p * 1152 + ck];
    T[e] = a;
  } else if (bid < 2336) {
    int idx = bid - 288;
    int b = idx >> 10, rem = idx & 1023;
    int y = rem >> 3, xg = (rem & 7) << 5;
    for (int it = tid; it < 32 * 128; it += 256) {
      int c = it >> 5, xi = it & 31;
      tile[xi * 129 + c] = x[(((size_t)b * 128 + c) * 128 + y) * 256 + xg + xi];
    }
    __syncthreads();
    for (int it = tid; it < 32 * 16; it += 256) {
      int xi = it >> 4, cs = it & 15;
      ushort8 v;
      #pragma unroll
      for (int e = 0; e < 8; ++e) v[e] = f2bf(tile[xi * 129 + cs * 8 + e]);
      *(ushort8*)(xh + (((size_t)b * 128 + y) * 256 + xg + xi) * 128 + cs * 8) = v;
    }
  } else {
    int e = (bid - 2336) * 256 + tid;
    if (e >= 9 * 128 * 256) return;
    int k = e >> 15, rem = e & 32767;
    int ii = rem >> 8, jj = rem & 255;
    float dy = offset[(2 * k) * 32768 + rem];
    float dx = offset[(2 * k + 1) * 32768 + rem];
    int ki = k / 3, kj = k % 3;
    float py = (float)(ii - 1 + ki) + dy;
    float px = (float)(jj - 1 + kj) + dx;
    float fy0 = floorf(py), fx0 = floorf(px);
    int y0 = (int)fy0, x0 = (int)fx0;
    float fy = py - fy0, fx = px - fx0;
    int ys[2] = {y0, y0 + 1};
    int xs_[2] = {x0, x0 + 1};
    float wy[2] = {1.f - fy, fy}, wx[2] = {1.f - fx, fx};
    int4v o;
    float4v w;
    #pragma unroll
    for (int cy = 0; cy < 2; ++cy) {
      #pragma unroll
      for (int cx = 0; cx < 2; ++cx) {
        int yy = ys[cy], xx = xs_[cx];
        bool valid = (yy >= 0) && (yy < HH) && (xx < WW) && (xx >= 0);
        int yc = min(max(yy, 0), HH - 1), xc = min(max(xx, 0), WW - 1);
        int off = (yc * WW + xc) * CIN_;
        float wv = valid ? wy[cy] * wx[cx] : 0.f;
        int ci = cy * 2 + cx;
        if (ci == 0) { o.x = off; w.x = wv; }
        else if (ci == 1) { o.y = off; w.y = wv; }
        else if (ci == 2) { o.z = off; w.z = wv; }
        else { o.w = off; w.w = wv; }
      }
    }
    mo[e] = o;
    mw[e] = w;
  }
}

// ---------------- merged prep #2: effective weights (1152 blk) + bias (1 blk)
__global__ __launch_bounds__(256) void k_pre2(
    const float* __restrict__ up_w, const float* __restrict__ weight,
    const float* __restrict__ T, const float* __restrict__ scale,
    unsigned short* __restrict__ wdef, unsigned short* __restrict__ wstd,
    const float* __restrict__ down_w, const float* __restrict__ bias,
    float* __restrict__ beff) {
  __shared__ float sd[32];
  int bid = blockIdx.x;
  int t = threadIdx.x;
  if (bid < 1152) {
    int e = bid * 256 + t;
    if (e >= 2 * 9 * 128 * 128) return;
    int s = e / 147456, r = e % 147456;
    int tap = r / 16384, o = (r / 128) % 128, c = r % 128;
    int ck = c * 9 + tap;
    const float* Ts = T + s * 36864;
    float a = 0.f;
    #pragma unroll
    for (int d = 0; d < 32; ++d) a += up_w[o * 32 + d] * Ts[d * 1152 + ck];
    float scl = scale[0];
    int idx = ((tap * 4 + (c >> 5)) * 128 + o) * 32 + (c & 31);
    if (s == 1) {
      wstd[idx] = f2bf(weight[o * 1152 + ck] + scl * a);
    } else {
      wdef[idx] = f2bf(scl * a);
    }
  } else {
    if (t < 32) {
      float a = 0.f;
      for (int p = 0; p < 128; ++p)
        a += (down_w[t * 256 + p] + down_w[t * 256 + 128 + p]) * bias[p];
      sd[t] = a;
    }
    __syncthreads();
    if (t < 128) {
      float a = 0.f;
      #pragma unroll
      for (int d = 0; d < 32; ++d) a += up_w[t * 32 + d] * sd[d];
      beff[t] = bias[t] + scale[0] * a;
    }
  }
}

// ---------------- Main: P/C waves + 2-row weight reuse + persistent x-window.
// Block = 128 out-ch x {2 row-tiles of 64 px}. 512 thr = 8 waves:
//   waves 0-3 producers: fill 4-row x-window once; stage deform tap t during
//     even phase v=2t into a SINGLE 32KB dbuf (consumed at v=2t+1).
//   waves 4-7 consumers: std taps read the window with (ki,kj) shift (no
//     staging!), deform taps read dbuf; A-fragments once per tap, both tiles.
// LDS: window 4x66x256B = 66KB + dbuf 32KB = 98KB -> 1 block/CU.
__global__ __launch_bounds__(512, 4) void k_main(
    const unsigned short* __restrict__ xh,
    const int4v* __restrict__ mo, const float4v* __restrict__ mw,
    const unsigned short* __restrict__ wstd, const unsigned short* __restrict__ wdef,
    const float* __restrict__ beff, float* __restrict__ out) {
  __shared__ __align__(16) unsigned short win[4 * 66 * 128];   // 67,584 B
  __shared__ __align__(16) unsigned short dbuf[2][64 * 128];   // 32,768 B (2 tiles)

  // XCD-contiguous bijective swizzle; 512 % 8 == 0.
  int orig = blockIdx.x;
  int t = ((orig & 7) << 6) + (orig >> 3);
  int b = t >> 8, ip = (t >> 2) & 63, j0 = (t & 3) << 6;
  int i0 = ip << 1;  // rows i0, i0+1
  int tid = threadIdx.x;
  const unsigned short* xb = xh + (size_t)b * (HH * WW * CIN_);

  int wid = tid >> 6;
  bool producer = wid < 4;

  if (producer) {
    int slot = tid & 15, pg = tid >> 4;  // 16 lanes cover one pixel's 256B
    int ce = slot * 8;

    // ---- one-time window fill: rows i0-1..i0+2, cols j0-1..j0+64 ----
    for (int it = tid; it < 4 * 66 * 16; it += 256) {
      int s = it & 15, colr = it >> 4;
      int c = colr % 66, r = colr / 66;
      int gy = i0 - 1 + r, gx = j0 - 1 + c;
      uint4v vv = {};
      if ((unsigned)gy < (unsigned)HH && (unsigned)gx < (unsigned)WW)
        vv = *(const uint4v*)(xb + (size_t)(gy * WW + gx) * CIN_ + s * 8);
      *(uint4v*)((char*)win + ((r * 66 + c) << 8) + ((s ^ (c & 15)) << 4)) = vv;
    }

    auto COMB = [&](uint4v* g, float4v w, int q, unsigned short* buf) {
      int p = q * 16 + pg;
      uint4v r;
      #pragma unroll
      for (int wi = 0; wi < 4; ++wi) {
        unsigned u0 = g[0][wi], u1 = g[1][wi], u2 = g[2][wi], u3 = g[3][wi];
        float2v f0 = {__builtin_bit_cast(float, u0 << 16), __builtin_bit_cast(float, u0 & 0xffff0000u)};
        float2v f1 = {__builtin_bit_cast(float, u1 << 16), __builtin_bit_cast(float, u1 & 0xffff0000u)};
        float2v f2 = {__builtin_bit_cast(float, u2 << 16), __builtin_bit_cast(float, u2 & 0xffff0000u)};
        float2v f3 = {__builtin_bit_cast(float, u3 << 16), __builtin_bit_cast(float, u3 & 0xffff0000u)};
        float2v s = w.x * f0 + w.y * f1 + w.z * f2 + w.w * f3;
        unsigned rr;
        asm("v_cvt_pk_bf16_f32 %0, %1, %2" : "=v"(rr) : "v"(s.x), "v"(s.y));
        r[wi] = rr;
      }
      *(uint4v*)((char*)buf + (p << 8) + ((slot ^ (p & 15)) << 4)) = r;
    };

    auto STAGE_DEF = [&](int tap, int i, unsigned short* buf) {
      int4v o;
      float4v wq0, wq1;
      uint4v g0[4], g1[4];
      int mbase = (tap * HH + i) * WW + j0 + pg;

      o = mo[mbase]; wq0 = mw[mbase];
      g0[0] = *(const uint4v*)(xb + o.x + ce);
      g0[1] = *(const uint4v*)(xb + o.y + ce);
      g0[2] = *(const uint4v*)(xb + o.z + ce);
      g0[3] = *(const uint4v*)(xb + o.w + ce);
      o = mo[mbase + 16]; wq1 = mw[mbase + 16];
      g1[0] = *(const uint4v*)(xb + o.x + ce);
      g1[1] = *(const uint4v*)(xb + o.y + ce);
      g1[2] = *(const uint4v*)(xb + o.z + ce);
      g1[3] = *(const uint4v*)(xb + o.w + ce);

      COMB(g0, wq0, 0, buf);
      o = mo[mbase + 32]; wq0 = mw[mbase + 32];
      g0[0] = *(const uint4v*)(xb + o.x + ce);
      g0[1] = *(const uint4v*)(xb + o.y + ce);
      g0[2] = *(const uint4v*)(xb + o.z + ce);
      g0[3] = *(const uint4v*)(xb + o.w + ce);
      COMB(g1, wq1, 1, buf);
      o = mo[mbase + 48]; wq1 = mw[mbase + 48];
      g1[0] = *(const uint4v*)(xb + o.x + ce);
      g1[1] = *(const uint4v*)(xb + o.y + ce);
      g1[2] = *(const uint4v*)(xb + o.z + ce);
      g1[3] = *(const uint4v*)(xb + o.w + ce);
      COMB(g0, wq0, 2, buf);
      COMB(g1, wq1, 3, buf);
    };

    __syncthreads();  // window ready
    for (int v = 0; v < 18; ++v) {
      if (!(v & 1) && v < 17) {
        int tap = v >> 1;  // deform tap t staged during std phase v=2t
        STAGE_DEF(tap, i0, dbuf[0]);
        STAGE_DEF(tap, i0 + 1, dbuf[1]);
      }
      __syncthreads();
    }
  } else {
    // ---- consumer path ----
    int lane = tid & 63;
    int cw = wid - 4;
    int obase = cw << 5;
    int lrow = lane & 15, lhi = lane >> 4;

    f32x4 acc[2][2][4] = {};  // [tile][am][bn]

    __syncthreads();  // window ready
    for (int v = 0; v < 18; ++v) {
      const unsigned short* wt = ((v & 1) ? wdef : wstd) + (size_t)(v >> 1) * 16384;
      short8 af[4][2];
      #pragma unroll
      for (int cc = 0; cc < 4; ++cc)
        #pragma unroll
        for (int am = 0; am < 2; ++am)
          af[cc][am] = *(const short8*)(wt + ((size_t)(cc * 128 + obase + am * 16 + lrow)) * 32 + lhi * 8);

      if (v & 1) {
        // deform: read single dbuf (staged during previous even phase)
        #pragma unroll
        for (int tile = 0; tile < 2; ++tile) {
          const unsigned short* cur = dbuf[tile];
          #pragma unroll
          for (int cc = 0; cc < 4; ++cc) {
            short8 bfr[4];
            #pragma unroll
            for (int bn = 0; bn < 4; ++bn) {
              int pp = bn * 16 + lrow;
              bfr[bn] = *(const short8*)((const char*)cur + (pp << 8) +
                                         (((cc * 4 + lhi) ^ lrow) << 4));
            }
            #pragma unroll
            for (int am = 0; am < 2; ++am)
              #pragma unroll
              for (int bn = 0; bn < 4; ++bn)
                acc[tile][am][bn] = __builtin_amdgcn_mfma_f32_16x16x32_bf16(af[cc][am], bfr[bn], acc[tile][am][bn], 0, 0, 0);
          }
        }
      } else {
        // std tap: read persistent window with (ki,kj) shift
        int tap = v >> 1;
        int ki = tap / 3, kj = tap % 3;
        #pragma unroll
        for (int tile = 0; tile < 2; ++tile) {
          int wrow = tile + ki;
          #pragma unroll
          for (int cc = 0; cc < 4; ++cc) {
            short8 bfr[4];
            #pragma unroll
            for (int bn = 0; bn < 4; ++bn) {
              int wcol = bn * 16 + lrow + kj;
              bfr[bn] = *(const short8*)((const char*)win + ((wrow * 66 + wcol) << 8) +
                                         (((cc * 4 + lhi) ^ (wcol & 15)) << 4));
            }
            #pragma unroll
            for (int am = 0; am < 2; ++am)
              #pragma unroll
              for (int bn = 0; bn < 4; ++bn)
                acc[tile][am][bn] = __builtin_amdgcn_mfma_f32_16x16x32_bf16(af[cc][am], bfr[bn], acc[tile][am][bn], 0, 0, 0);
          }
        }
      }
      __syncthreads();
    }

    // epilogue: + b_eff, store f32 NCHW, both tiles
    #pragma unroll
    for (int tile = 0; tile < 2; ++tile) {
      #pragma unroll
      for (int am = 0; am < 2; ++am) {
        #pragma unroll
        for (int bn = 0; bn < 4; ++bn) {
          int jg = j0 + bn * 16 + lrow;
          #pragma unroll
          for (int r = 0; r < 4; ++r) {
            int o = obase + am * 16 + lhi * 4 + r;
            out[(((size_t)b * COUT_ + o) * HH + (i0 + tile)) * WW + jg] =
                acc[tile][am][bn][r] + beff[o];
          }
        }
      }
    }
  }
}

extern "C" void kernel_launch(void* const* d_in, const int* in_sizes, int n_in,
                              void* d_out, int out_size, void* d_ws, size_t ws_size,
                              hipStream_t stream) {
  const float* x      = (const float*)d_in[0];
  const float* offset = (const float*)d_in[1];
  const float* weight = (const float*)d_in[2];
  const float* bias   = (const float*)d_in[3];
  const float* down_w = (const float*)d_in[4];
  const float* up_w   = (const float*)d_in[5];
  const float* scale  = (const float*)d_in[6];
  float* out = (float*)d_out;

  char* ws = (char*)d_ws;
  unsigned short* xh   = (unsigned short*)(ws);              // 16,777,216 B
  int4v* mo            = (int4v*)(ws + 16777216);            //  4,718,592 B
  float4v* mw          = (float4v*)(ws + 21495808);          //  4,718,592 B
  unsigned short* wstd = (unsigned short*)(ws + 26214400);   //    294,912 B
  unsigned short* wdef = (unsigned short*)(ws + 26509312);   //    294,912 B
  float* T             = (float*)(ws + 26804224);            //    294,912 B
  float* beff          = (float*)(ws + 27099136);            //        512 B

  k_pre1<<<dim3(3488), dim3(256), 0, stream>>>(down_w, weight, T, x, xh, offset, mo, mw);
  k_pre2<<<dim3(1153), dim3(256), 0, stream>>>(up_w, weight, T, scale, wdef, wstd, down_w, bias, beff);
  k_main<<<dim3(512), dim3(512), 0, stream>>>(xh, mo, mw, wstd, wdef, beff, out);
}

// Round 18
// 93.739 us; speedup vs baseline: 1.2440x; 1.2440x over previous
//
#include <hip/hip_runtime.h>
#include <hip/hip_bf16.h>

typedef __attribute__((ext_vector_type(8))) short short8;
typedef __attribute__((ext_vector_type(8))) unsigned short ushort8;
typedef __attribute__((ext_vector_type(4))) float f32x4;
typedef __attribute__((ext_vector_type(4))) int int4v;
typedef __attribute__((ext_vector_type(4))) float float4v;
typedef __attribute__((ext_vector_type(2))) float float2v;
typedef __attribute__((ext_vector_type(4))) unsigned int uint4v;

#define HH 128
#define WW 256
#define CIN_ 128
#define COUT_ 128

__device__ __forceinline__ unsigned short f2bf(float f) {
  union { __hip_bfloat16 h; unsigned short u; } v;
  v.h = __float2bfloat16(f);
  return v.u;
}

// ---------------- merged prep #1: T (288 blk) + nhwc (2048 blk) + meta (1152 blk)
__global__ __launch_bounds__(256) void k_pre1(
    const float* __restrict__ down_w, const float* __restrict__ weight,
    float* __restrict__ T,
    const float* __restrict__ x, unsigned short* __restrict__ xh,
    const float* __restrict__ offset, int4v* __restrict__ mo,
    float4v* __restrict__ mw) {
  __shared__ float tile[32 * 129];
  int bid = blockIdx.x;
  int tid = threadIdx.x;

  if (bid < 288) {
    int e = bid * 256 + tid;
    if (e >= 2 * 32 * 1152) return;
    int s = e / 36864, r = e % 36864, d = r / 1152, ck = r % 1152;
    float a = 0.f;
    #pragma unroll 4
    for (int p = 0; p < 128; ++p)
      a += down_w[d * 256 + s * 128 + p] * weight[p * 1152 + ck];
    T[e] = a;
  } else if (bid < 2336) {
    int idx = bid - 288;
    int b = idx >> 10, rem = idx & 1023;
    int y = rem >> 3, xg = (rem & 7) << 5;
    for (int it = tid; it < 32 * 128; it += 256) {
      int c = it >> 5, xi = it & 31;
      tile[xi * 129 + c] = x[(((size_t)b * 128 + c) * 128 + y) * 256 + xg + xi];
    }
    __syncthreads();
    for (int it = tid; it < 32 * 16; it += 256) {
      int xi = it >> 4, cs = it & 15;
      ushort8 v;
      #pragma unroll
      for (int e = 0; e < 8; ++e) v[e] = f2bf(tile[xi * 129 + cs * 8 + e]);
      *(ushort8*)(xh + (((size_t)b * 128 + y) * 256 + xg + xi) * 128 + cs * 8) = v;
    }
  } else {
    int e = (bid - 2336) * 256 + tid;
    if (e >= 9 * 128 * 256) return;
    int k = e >> 15, rem = e & 32767;
    int ii = rem >> 8, jj = rem & 255;
    float dy = offset[(2 * k) * 32768 + rem];
    float dx = offset[(2 * k + 1) * 32768 + rem];
    int ki = k / 3, kj = k % 3;
    float py = (float)(ii - 1 + ki) + dy;
    float px = (float)(jj - 1 + kj) + dx;
    float fy0 = floorf(py), fx0 = floorf(px);
    int y0 = (int)fy0, x0 = (int)fx0;
    float fy = py - fy0, fx = px - fx0;
    int ys[2] = {y0, y0 + 1};
    int xs_[2] = {x0, x0 + 1};
    float wy[2] = {1.f - fy, fy}, wx[2] = {1.f - fx, fx};
    int4v o;
    float4v w;
    #pragma unroll
    for (int cy = 0; cy < 2; ++cy) {
      #pragma unroll
      for (int cx = 0; cx < 2; ++cx) {
        int yy = ys[cy], xx = xs_[cx];
        bool valid = (yy >= 0) && (yy < HH) && (xx < WW) && (xx >= 0);
        int yc = min(max(yy, 0), HH - 1), xc = min(max(xx, 0), WW - 1);
        int off = (yc * WW + xc) * CIN_;
        float wv = valid ? wy[cy] * wx[cx] : 0.f;
        int ci = cy * 2 + cx;
        if (ci == 0) { o.x = off; w.x = wv; }
        else if (ci == 1) { o.y = off; w.y = wv; }
        else if (ci == 2) { o.z = off; w.z = wv; }
        else { o.w = off; w.w = wv; }
      }
    }
    mo[e] = o;
    mw[e] = w;
  }
}

// ---------------- merged prep #2: effective weights (1152 blk) + bias (1 blk)
__global__ __launch_bounds__(256) void k_pre2(
    const float* __restrict__ up_w, const float* __restrict__ weight,
    const float* __restrict__ T, const float* __restrict__ scale,
    unsigned short* __restrict__ wdef, unsigned short* __restrict__ wstd,
    const float* __restrict__ down_w, const float* __restrict__ bias,
    float* __restrict__ beff) {
  __shared__ float sd[32];
  int bid = blockIdx.x;
  int t = threadIdx.x;
  if (bid < 1152) {
    int e = bid * 256 + t;
    if (e >= 2 * 9 * 128 * 128) return;
    int s = e / 147456, r = e % 147456;
    int tap = r / 16384, o = (r / 128) % 128, c = r % 128;
    int ck = c * 9 + tap;
    const float* Ts = T + s * 36864;
    float a = 0.f;
    #pragma unroll
    for (int d = 0; d < 32; ++d) a += up_w[o * 32 + d] * Ts[d * 1152 + ck];
    float scl = scale[0];
    int idx = ((tap * 4 + (c >> 5)) * 128 + o) * 32 + (c & 31);
    if (s == 1) {
      wstd[idx] = f2bf(weight[o * 1152 + ck] + scl * a);
    } else {
      wdef[idx] = f2bf(scl * a);
    }
  } else {
    if (t < 32) {
      float a = 0.f;
      for (int p = 0; p < 128; ++p)
        a += (down_w[t * 256 + p] + down_w[t * 256 + 128 + p]) * bias[p];
      sd[t] = a;
    }
    __syncthreads();
    if (t < 128) {
      float a = 0.f;
      #pragma unroll
      for (int d = 0; d < 32; ++d) a += up_w[t * 32 + d] * sd[d];
      beff[t] = bias[t] + scale[0] * a;
    }
  }
}

// ---------------- Main: P/C waves + 2-row-tile weight reuse (R16 optimum).
// Block = 128 out-ch x {2 tiles of 64 px at rows i0, i0+1}. 512 thr = 8 waves:
//   waves 0-3 producers (stage tap v+1 for both tiles),
//   waves 4-7 consumers (o-quarter; A-fragments loaded ONCE per tap, MFMA both tiles).
// 512 blocks -> weight L2 line-requests halve vs per-row blocks.
__global__ __launch_bounds__(512, 4) void k_main(
    const unsigned short* __restrict__ xh,
    const int4v* __restrict__ mo, const float4v* __restrict__ mw,
    const unsigned short* __restrict__ wstd, const unsigned short* __restrict__ wdef,
    const float* __restrict__ beff, float* __restrict__ out) {
  __shared__ __align__(16) unsigned short sbuf[2][2][64 * 128];  // dbuf x tile x 16KB = 64KB

  // XCD-contiguous bijective swizzle; 512 % 8 == 0; 64 consecutive t per XCD
  // = 32 consecutive rows (~2.2 MB gather set, L2-resident).
  int orig = blockIdx.x;
  int t = ((orig & 7) << 6) + (orig >> 3);
  int b = t >> 8, ip = (t >> 2) & 63, j0 = (t & 3) << 6;
  int i0 = ip << 1;  // rows i0 and i0+1
  int tid = threadIdx.x;
  const unsigned short* xb = xh + (size_t)b * (HH * WW * CIN_);

  int wid = tid >> 6;
  bool producer = wid < 4;

  if (producer) {
    int slot = tid & 15, pg = tid >> 4;  // pg 0..15; 16 lanes cover one pixel's 256B
    int ce = slot * 8;

    auto COMB = [&](uint4v* g, float4v w, int q, unsigned short* buf) {
      int p = q * 16 + pg;
      uint4v r;
      #pragma unroll
      for (int wi = 0; wi < 4; ++wi) {
        unsigned u0 = g[0][wi], u1 = g[1][wi], u2 = g[2][wi], u3 = g[3][wi];
        float2v f0 = {__builtin_bit_cast(float, u0 << 16), __builtin_bit_cast(float, u0 & 0xffff0000u)};
        float2v f1 = {__builtin_bit_cast(float, u1 << 16), __builtin_bit_cast(float, u1 & 0xffff0000u)};
        float2v f2 = {__builtin_bit_cast(float, u2 << 16), __builtin_bit_cast(float, u2 & 0xffff0000u)};
        float2v f3 = {__builtin_bit_cast(float, u3 << 16), __builtin_bit_cast(float, u3 & 0xffff0000u)};
        float2v s = w.x * f0 + w.y * f1 + w.z * f2 + w.w * f3;
        unsigned rr;
        asm("v_cvt_pk_bf16_f32 %0, %1, %2" : "=v"(rr) : "v"(s.x), "v"(s.y));
        r[wi] = rr;
      }
      *(uint4v*)((char*)buf + (p << 8) + ((slot ^ (p & 15)) << 4)) = r;
    };

    auto STAGE_DEF = [&](int tap, int i, unsigned short* buf) {
      int4v o;
      float4v wq0, wq1;
      uint4v g0[4], g1[4];
      int mbase = (tap * HH + i) * WW + j0 + pg;

      o = mo[mbase]; wq0 = mw[mbase];
      g0[0] = *(const uint4v*)(xb + o.x + ce);
      g0[1] = *(const uint4v*)(xb + o.y + ce);
      g0[2] = *(const uint4v*)(xb + o.z + ce);
      g0[3] = *(const uint4v*)(xb + o.w + ce);
      o = mo[mbase + 16]; wq1 = mw[mbase + 16];
      g1[0] = *(const uint4v*)(xb + o.x + ce);
      g1[1] = *(const uint4v*)(xb + o.y + ce);
      g1[2] = *(const uint4v*)(xb + o.z + ce);
      g1[3] = *(const uint4v*)(xb + o.w + ce);

      COMB(g0, wq0, 0, buf);
      o = mo[mbase + 32]; wq0 = mw[mbase + 32];
      g0[0] = *(const uint4v*)(xb + o.x + ce);
      g0[1] = *(const uint4v*)(xb + o.y + ce);
      g0[2] = *(const uint4v*)(xb + o.z + ce);
      g0[3] = *(const uint4v*)(xb + o.w + ce);
      COMB(g1, wq1, 1, buf);
      o = mo[mbase + 48]; wq1 = mw[mbase + 48];
      g1[0] = *(const uint4v*)(xb + o.x + ce);
      g1[1] = *(const uint4v*)(xb + o.y + ce);
      g1[2] = *(const uint4v*)(xb + o.z + ce);
      g1[3] = *(const uint4v*)(xb + o.w + ce);
      COMB(g0, wq0, 2, buf);
      COMB(g1, wq1, 3, buf);
    };

    auto STAGE_STD = [&](int tap, int i, unsigned short* buf) {
      int ki = tap / 3, kj = tap % 3;
      int gy = i - 1 + ki;
      bool oky = (unsigned)gy < (unsigned)HH;
      uint4v s[4];
      #pragma unroll
      for (int q = 0; q < 4; ++q) {
        int p = q * 16 + pg;
        int gx = j0 + p - 1 + kj;
        uint4v vv = {};
        if (oky && (unsigned)gx < (unsigned)WW)
          vv = *(const uint4v*)(xb + (size_t)(gy * WW + gx) * CIN_ + ce);
        s[q] = vv;
      }
      #pragma unroll
      for (int q = 0; q < 4; ++q) {
        int p = q * 16 + pg;
        *(uint4v*)((char*)buf + (p << 8) + ((slot ^ (p & 15)) << 4)) = s[q];
      }
    };

    STAGE_STD(0, i0, sbuf[0][0]);
    STAGE_STD(0, i0 + 1, sbuf[0][1]);
    __syncthreads();
    for (int v = 0; v < 18; ++v) {
      if (v < 17) {
        int nv = v + 1;
        if (nv & 1) {
          STAGE_DEF(nv >> 1, i0, sbuf[nv & 1][0]);
          STAGE_DEF(nv >> 1, i0 + 1, sbuf[nv & 1][1]);
        } else {
          STAGE_STD(nv >> 1, i0, sbuf[nv & 1][0]);
          STAGE_STD(nv >> 1, i0 + 1, sbuf[nv & 1][1]);
        }
      }
      __syncthreads();
    }
  } else {
    // ---- consumer path: A-fragments loaded once per tap, both tiles MFMA'd ----
    int lane = tid & 63;
    int cw = wid - 4;             // 0..3: o-quarter
    int obase = cw << 5;
    int lrow = lane & 15, lhi = lane >> 4;

    f32x4 acc[2][2][4] = {};      // [tile][am][bn]

    __syncthreads();  // matches producer prologue barrier
    for (int v = 0; v < 18; ++v) {
      const unsigned short* wt = ((v & 1) ? wdef : wstd) + (size_t)(v >> 1) * 16384;
      short8 af[4][2];
      #pragma unroll
      for (int cc = 0; cc < 4; ++cc)
        #pragma unroll
        for (int am = 0; am < 2; ++am)
          af[cc][am] = *(const short8*)(wt + ((size_t)(cc * 128 + obase + am * 16 + lrow)) * 32 + lhi * 8);
      #pragma unroll
      for (int tile = 0; tile < 2; ++tile) {
        const unsigned short* cur = sbuf[v & 1][tile];
        #pragma unroll
        for (int cc = 0; cc < 4; ++cc) {
          short8 bfr[4];
          #pragma unroll
          for (int bn = 0; bn < 4; ++bn) {
            int pp = bn * 16 + lrow;
            bfr[bn] = *(const short8*)((const char*)cur + (pp << 8) +
                                       (((cc * 4 + lhi) ^ lrow) << 4));
          }
          #pragma unroll
          for (int am = 0; am < 2; ++am)
            #pragma unroll
            for (int bn = 0; bn < 4; ++bn)
              acc[tile][am][bn] = __builtin_amdgcn_mfma_f32_16x16x32_bf16(af[cc][am], bfr[bn], acc[tile][am][bn], 0, 0, 0);
        }
      }
      __syncthreads();
    }

    // epilogue: + b_eff, store f32 NCHW, both tiles
    #pragma unroll
    for (int tile = 0; tile < 2; ++tile) {
      #pragma unroll
      for (int am = 0; am < 2; ++am) {
        #pragma unroll
        for (int bn = 0; bn < 4; ++bn) {
          int jg = j0 + bn * 16 + lrow;
          #pragma unroll
          for (int r = 0; r < 4; ++r) {
            int o = obase + am * 16 + lhi * 4 + r;
            out[(((size_t)b * COUT_ + o) * HH + (i0 + tile)) * WW + jg] =
                acc[tile][am][bn][r] + beff[o];
          }
        }
      }
    }
  }
}

extern "C" void kernel_launch(void* const* d_in, const int* in_sizes, int n_in,
                              void* d_out, int out_size, void* d_ws, size_t ws_size,
                              hipStream_t stream) {
  const float* x      = (const float*)d_in[0];
  const float* offset = (const float*)d_in[1];
  const float* weight = (const float*)d_in[2];
  const float* bias   = (const float*)d_in[3];
  const float* down_w = (const float*)d_in[4];
  const float* up_w   = (const float*)d_in[5];
  const float* scale  = (const float*)d_in[6];
  float* out = (float*)d_out;

  char* ws = (char*)d_ws;
  unsigned short* xh   = (unsigned short*)(ws);              // 16,777,216 B
  int4v* mo            = (int4v*)(ws + 16777216);            //  4,718,592 B
  float4v* mw          = (float4v*)(ws + 21495808);          //  4,718,592 B
  unsigned short* wstd = (unsigned short*)(ws + 26214400);   //    294,912 B
  unsigned short* wdef = (unsigned short*)(ws + 26509312);   //    294,912 B
  float* T             = (float*)(ws + 26804224);            //    294,912 B
  float* beff          = (float*)(ws + 27099136);            //        512 B

  k_pre1<<<dim3(3488), dim3(256), 0, stream>>>(down_w, weight, T, x, xh, offset, mo, mw);
  k_pre2<<<dim3(1153), dim3(256), 0, stream>>>(up_w, weight, T, scale, wdef, wstd, down_w, bias, beff);
  k_main<<<dim3(512), dim3(512), 0, stream>>>(xh, mo, mw, wstd, wdef, beff, out);
}